// Round 6
// baseline (239.613 us; speedup 1.0000x reference)
//
#include <hip/hip_runtime.h>
#include <math.h>

#define NPAIR 131072          // 8192 freqs x 16 channels
#define STEPS 19
#define VMD_BLOCKS 256        // x 512 threads = NPAIR
#define ND_BANKS 16

// XOR swizzle: spreads strided radix-8 writes across banks; keeps contiguous free
#define SW(a) ((a) ^ (((a) >> 5) & 31))

#define LD_RLX(p)    __hip_atomic_load((p),       __ATOMIC_RELAXED, __HIP_MEMORY_SCOPE_AGENT)
#define ST_RLX(p,v)  __hip_atomic_store((p),(v),  __ATOMIC_RELAXED, __HIP_MEMORY_SCOPE_AGENT)

__device__ __forceinline__ float2 cadd(float2 a, float2 b){ return make_float2(a.x+b.x, a.y+b.y); }
__device__ __forceinline__ float2 csub(float2 a, float2 b){ return make_float2(a.x-b.x, a.y-b.y); }
__device__ __forceinline__ float2 cmul(float2 a, float2 b){
    return make_float2(a.x*b.x - a.y*b.y, a.x*b.y + a.y*b.x);
}
template<int SGN>
__device__ __forceinline__ float2 imul(float2 a){   // multiply by e^{SGN*i*pi/2}
    return (SGN > 0) ? make_float2(-a.y, a.x) : make_float2(a.y, -a.x);
}

// 8-point DFT: y_k = sum_r a_r e^{SGN*2pi i r k/8}
template<int SGN>
__device__ __forceinline__ void dft8(const float2* a, float2* y){
    const float C = 0.70710678118654752f;
    const float sg = (SGN > 0) ? 1.f : -1.f;
    float2 t0 = cadd(a[0], a[4]), t1 = csub(a[0], a[4]);
    float2 t2 = cadd(a[2], a[6]), t3 = imul<SGN>(csub(a[2], a[6]));
    float2 E0 = cadd(t0, t2), E2 = csub(t0, t2), E1 = cadd(t1, t3), E3 = csub(t1, t3);
    float2 s0 = cadd(a[1], a[5]), s1 = csub(a[1], a[5]);
    float2 s2 = cadd(a[3], a[7]), s3 = imul<SGN>(csub(a[3], a[7]));
    float2 O0 = cadd(s0, s2), O2 = csub(s0, s2), O1 = cadd(s1, s3), O3 = csub(s1, s3);
    float2 w1 = make_float2(C, sg * C), w3 = make_float2(-C, sg * C);
    float2 R0 = O0, R1 = cmul(O1, w1), R2 = imul<SGN>(O2), R3 = cmul(O3, w3);
    y[0] = cadd(E0, R0); y[4] = csub(E0, R0);
    y[1] = cadd(E1, R1); y[5] = csub(E1, R1);
    y[2] = cadd(E2, R2); y[6] = csub(E2, R2);
    y[3] = cadd(E3, R3); y[7] = csub(E3, R3);
}

// ===== in-LDS 8192-pt Stockham FFT: 4 radix-8 passes + 1 radix-2, 1024 threads =====
template<int SGN>
__device__ void lds_fft8192_r8(float2* lds, int tid){
    #pragma unroll
    for (int pi = 0; pi < 4; pi++){
        int ls = 3 * pi;
        int s  = 1 << ls;
        int nn = 8192 >> ls;
        int q = tid & (s - 1);
        float2 a[8], y[8];
        #pragma unroll
        for (int r = 0; r < 8; r++) a[r] = lds[SW(tid + (r << 10))];
        __syncthreads();
        dft8<SGN>(a, y);
        int p = tid >> ls;
        float ang = (float)(2 * p) / (float)nn;
        float sn, cs;
        sincospif(SGN > 0 ? ang : -ang, &sn, &cs);   // w = e^{SGN*2pi i p/nn}
        float2 w = make_float2(cs, sn);
        float2 wk = make_float2(1.f, 0.f);
        int o = q + ((tid - q) << 3);                 // q + 8*s*p
        lds[SW(o)] = y[0];
        #pragma unroll
        for (int k = 1; k < 8; k++){
            wk = cmul(wk, w);
            lds[SW(o + (k << ls))] = cmul(y[k], wk);
        }
        __syncthreads();
    }
    #pragma unroll
    for (int w4 = 0; w4 < 4; w4++){                   // final radix-2, twiddle-free
        int idx = (w4 << 10) + tid;
        float2 a = lds[SW(idx)], b = lds[SW(idx + 4096)];
        lds[SW(idx)]        = cadd(a, b);
        lds[SW(idx + 4096)] = csub(a, b);
    }
    __syncthreads();
}

// ===== stage A: mirror-extend + one FFT8192 per block (even/odd split radix half) ====
// R18: 32 blocks x 1 FFT. Split-radix combine fused into k_vmd_all's load.
// R19: FPTA/FPTB alias U's first 2 MB (dead before U written).
// R21: zero-fill of D fused here (saves a launch; kernel boundary orders it).
__global__ __launch_bounds__(1024) void k_stageA(const float* __restrict__ sig,
                                                 float2* __restrict__ FPTA,
                                                 float2* __restrict__ FPTB,
                                                 double* __restrict__ D){
    extern __shared__ float2 lds[];
    int tid  = threadIdx.x;
    int bb   = blockIdx.x;                   // bb = cw*2 + half
    // fused zerond: 32 blocks x 1024 threads cover 5400 doubles
    for (int zi = bb * 1024 + tid; zi < 5400; zi += 32768)
        D[zi] = 0.0;
    int cw   = bb >> 1, half = bb & 1;
    int cs   = (cw + 8) & 15;                // fftshift over channel axis
    const float* sp = sig + cs * 8192;
    #pragma unroll
    for (int r = 0; r < 8; r++){             // samples 2p+half of mirrored extension
        int p = r * 1024 + tid;
        int x = 2 * p + half;
        int mx = (x < 4096) ? (4095 - x) : ((x < 12288) ? (x - 4096) : (20479 - x));
        lds[SW(p)] = make_float2(sp[mx], 0.f);
    }
    __syncthreads();
    lds_fft8192_r8<-1>(lds, tid);
    float2* dst = (half == 0 ? FPTA : FPTB) + cw * 8192;
    #pragma unroll
    for (int r = 0; r < 8; r++){
        int j = r * 1024 + tid;
        dst[j] = lds[SW(j)];
    }
}

// ===== fused 19-step VMD: RMW-FREE dissemination barrier (R22) ====
// R16: all cross-block data via AGENT-scope (LLC) atomics — no fences needed.
// R17: role-splitting multi-value butterfly reduce (17 dbl-shfls vs 96).
// R18/R19 LESSON: polled-line accessor count AND RMW mix are the cost drivers.
// R22: the two 16-deep FAA trains (group + root counters) serialized at the
// LLC bank. Replaced with a store-only 2-hop dissemination:
//   arrive:  leader stores step+1 -> arr[grp][idx]       (16 wr / 1 rd per line)
//   hop 1 :  agg (idx==0) polls its arr line (one 64B read), then stores
//            step+1 -> rep[r][grp] for r=0..15           (fire-and-forget)
//   hop 2 :  every leader polls rep[grp][0..15] >= step+1 (16 wr / <=16 rd)
// Zero RMWs; chain ~4 dependent LLC RTs. Monotonic values, >= compares,
// all 256 blocks resident (1/CU) -> deadlock-free.
__global__ __launch_bounds__(512, 2) void k_vmd_all(const float2* __restrict__ FPTA,
                                                    const float2* __restrict__ FPTB,
                                                    float2* __restrict__ U,
                                                    double* __restrict__ D){
    double* NDB = D;
    int*    CNT = (int*)(D + 4864);   // arr: CNT[0..255], rep: CNT[256..511]

    int tid = blockIdx.x * 512 + threadIdx.x;   // [0,NPAIR), tid = cw*8192+j
    int j = tid & 8191;
    double fr = (double)j / 16384.0;
    // split-radix combine (was in stageA): F[j] = A[j] + e^{-i pi j/8192} B[j]
    float2 Av = FPTA[tid], Bv = FPTB[tid];
    float snw, cnw;
    sincospif(-(float)j / 8192.0f, &snw, &cnw);
    float2 tw = cmul(Bv, make_float2(cnw, snw));
    float2 fv = make_float2(Av.x + tw.x, Av.y + tw.y);
    double fx = fv.x, fy = fv.y;
    float urx[8], ury[8];
    double om[8];
    #pragma unroll
    for (int k = 0; k < 8; k++){ urx[k] = 0.f; ury[k] = 0.f; om[k] = 0.0625 * (double)k; }
    __shared__ double lred[8][16];
    __shared__ double ndls[256];
    __shared__ double om_s[8];
    int lane = threadIdx.x & 63, wv = threadIdx.x >> 6;
    int mybank = (blockIdx.x & (ND_BANKS - 1)) * 16;
    int grp = blockIdx.x >> 4;                  // 16 groups of 16 blocks
    int idx16 = blockIdx.x & 15;

    for (int step = 0; step < STEPS; step++){
        if (step > 0){
            #pragma unroll
            for (int k = 0; k < 8; k++) om[k] = om_s[k];
        }
        double sx = 0.0, sy = 0.0;
        #pragma unroll
        for (int k = 1; k < 8; k++){ sx += (double)urx[k]; sy += (double)ury[k]; }
        double lx = 0.0, ly = 0.0, nloc[8], dloc[8];
        #pragma unroll
        for (int k = 0; k < 8; k++){
            if (k > 0){ sx += lx - (double)urx[k]; sy += ly - (double)ury[k]; }
            double d = fr - om[k];
            double den = 1.0 + 2000.0 * d * d;
            double nx = (fx - sx) / den, ny = (fy - sy) / den;
            urx[k] = (float)nx; ury[k] = (float)ny;   // replicate complex64 carry
            lx = nx; ly = ny;
            double pw = nx * nx + ny * ny;
            nloc[k] = fr * pw; dloc[k] = pw;
        }
        // ---- multi-value butterfly reduce: 16 doubles across 64 lanes, 17 dbl-shfls ----
        // Level A (xor 32): bit5=0 lanes keep n-values, bit5=1 keep d-values.
        double s8[8];
        {
            bool hi = (lane & 32) != 0;
            #pragma unroll
            for (int k = 0; k < 8; k++){
                double t = hi ? nloc[k] : dloc[k];          // what we give away
                double r = __shfl_xor(t, 32);
                s8[k] = (hi ? dloc[k] : nloc[k]) + r;       // what we keep
            }
        }
        // Level B (xor 16): bit4=0 keeps idx 0..3, bit4=1 keeps idx 4..7.
        double s4v[4];
        {
            bool hi = (lane & 16) != 0;
            #pragma unroll
            for (int k = 0; k < 4; k++){
                double t = hi ? s8[k] : s8[k + 4];
                double r = __shfl_xor(t, 16);
                s4v[k] = (hi ? s8[k + 4] : s8[k]) + r;
            }
        }
        // Level C (xor 8)
        double s2v[2];
        {
            bool hi = (lane & 8) != 0;
            #pragma unroll
            for (int k = 0; k < 2; k++){
                double t = hi ? s4v[k] : s4v[k + 2];
                double r = __shfl_xor(t, 8);
                s2v[k] = (hi ? s4v[k + 2] : s4v[k]) + r;
            }
        }
        // Level D (xor 4)
        double sv;
        {
            bool hi = (lane & 4) != 0;
            double t = hi ? s2v[0] : s2v[1];
            double r = __shfl_xor(t, 4);
            sv = (hi ? s2v[1] : s2v[0]) + r;
        }
        // Final two full butterflies over the remaining 4-lane replication group
        sv += __shfl_xor(sv, 2);
        sv += __shfl_xor(sv, 1);
        // lane l holds wave-total for idx = l>>2 (idx<8: n_idx, idx>=8: d_{idx-8})
        if ((lane & 3) == 0) lred[wv][lane >> 2] = sv;
        __syncthreads();
        if (threadIdx.x < 16){
            double sum = 0.0;
            #pragma unroll
            for (int w = 0; w < 8; w++) sum += lred[w][threadIdx.x];
            atomicAdd(&NDB[step * 256 + mybank + threadIdx.x], sum);  // LLC f64 atomic
        }
        __syncthreads();      // all waves vmcnt-drained -> NDB adds COMPLETE at LLC
        if (step < STEPS - 1){
            if (threadIdx.x == 0){
                int tgt = step + 1;
                ST_RLX(&CNT[grp * 16 + idx16], tgt);          // arrive (store-only)
                if (idx16 == 0){                               // group aggregator
                    const int* a = &CNT[grp * 16];
                    bool ok;
                    do {
                        ok = true;
                        #pragma unroll
                        for (int i = 0; i < 16; i++) ok &= (LD_RLX(&a[i]) >= tgt);
                        if (!ok) __builtin_amdgcn_s_sleep(1);
                    } while (!ok);
                    #pragma unroll
                    for (int r = 0; r < 16; r++)               // replicate completion
                        ST_RLX(&CNT[256 + r * 16 + grp], tgt);
                }
                const int* rp = &CNT[256 + grp * 16];
                bool ok;
                do {
                    ok = true;
                    #pragma unroll
                    for (int g = 0; g < 16; g++) ok &= (LD_RLX(&rp[g]) >= tgt);
                    if (!ok) __builtin_amdgcn_s_sleep(1);
                } while (!ok);
            }
            __syncthreads();
            // parallel readback: 256 threads fetch one double each (LLC), sum in LDS
            if (threadIdx.x < 256)
                ndls[threadIdx.x] = LD_RLX(&NDB[step * 256 + threadIdx.x]);
            __syncthreads();
            if (threadIdx.x < 8){
                double n_ = 0.0, d_ = 0.0;
                #pragma unroll
                for (int bk = 0; bk < ND_BANKS; bk++){
                    n_ += ndls[bk * 16 + threadIdx.x];
                    d_ += ndls[bk * 16 + 8 + threadIdx.x];
                }
                om_s[threadIdx.x] = n_ / d_;
            }
            __syncthreads();
        }
    }
    #pragma unroll
    for (int k = 0; k < 8; k++) U[k * NPAIR + tid] = make_float2(urx[k], ury[k]);
}

// ===== stage C+D (R21): real-iFFT pack — 2 FFT8192 instead of 3 =====
// y = Re(iFFT16384(H)) = iFFT16384(hermitian_part(H)). Standard N/2 pack:
//   G[k] = (H[k]+H[k+M]) + i*W^k*(H[k]-H[k+M]),  W = e^{+i pi k/8192}, M=8192
//   z = iFFT8192(G)/N  ->  y[2n]=Re z[n], y[2n+1]=Im z[n]
// H (hermitized) from pos[]: H[k]=pos[k] (1<=k<=8191), H[0]=Re(pos[0]),
// H[M]=Re(pos[8191]), H[k+M]=conj(pos[M-k]) (1<=k<=M-1).
// Slice y_full[4096..12287] = z[2048..6143] interleaved.
// After: U32[b*16384 + t] = y[t];  U32[b*16384 + 8192 + t] = Re(Yf[(t+4096) mod 8192])
__global__ __launch_bounds__(1024) void k_stageCD(float2* __restrict__ U){
    extern __shared__ float2 lds[];
    int tid = threadIdx.x;
    int b = blockIdx.x;                      // b = k*16 + cw
    const float2* pos = U + b * 8192;
    float* slice = (float*)(U) + (size_t)b * 16384;
    const float inv = 1.0f / 16384.0f;
    // build G[p]
    #pragma unroll
    for (int r = 0; r < 8; r++){
        int p = r * 1024 + tid;
        float2 Hk, HkM;
        if (p == 0){
            Hk  = make_float2(pos[0].x, 0.f);
            HkM = make_float2(pos[8191].x, 0.f);
        } else {
            Hk = pos[p];
            float2 q2 = pos[8192 - p];
            HkM = make_float2(q2.x, -q2.y);
        }
        float2 S  = cadd(Hk, HkM);
        float2 Dv = csub(Hk, HkM);
        float sn, cn;
        sincospif((float)p / 8192.0f, &sn, &cn);     // W^p = e^{+i pi p/8192}
        float2 c = cmul(make_float2(cn, sn), Dv);
        lds[SW(p)] = make_float2(S.x - c.y, S.y + c.x);   // S + i*c
    }
    __syncthreads();
    lds_fft8192_r8<1>(lds, tid);
    // z[n] -> slice (only n in [2048,6144) land in the F/4..3F/4 slice)
    float2 zreg[4];
    #pragma unroll
    for (int q = 2; q < 6; q++){
        int n = q * 1024 + tid;
        float2 z = lds[SW(n)];
        zreg[q - 2] = make_float2(z.x * inv, z.y * inv);
        *(float2*)&slice[2 * n - 4096] = zreg[q - 2];     // coalesced 8B store
    }
    __syncthreads();
    // refill lds with the slice as complex (val, 0) for the forward FFT
    #pragma unroll
    for (int q = 0; q < 4; q++){
        int n = (q + 2) * 1024 + tid;
        int t = 2 * n - 4096;
        lds[SW(t)]     = make_float2(zreg[q].x, 0.f);
        lds[SW(t + 1)] = make_float2(zreg[q].y, 0.f);
    }
    __syncthreads();
    lds_fft8192_r8<-1>(lds, tid);            // forward FFT8192 of y-slice
    #pragma unroll
    for (int q = 0; q < 8; q++){
        int t = q * 1024 + tid;
        float2 Y = lds[SW(((q + 4) & 7) * 1024 + tid)];
        slice[8192 + t] = Y.x;               // Re(Yf[(t+4096) mod 8192]), coalesced
    }
}

// ===== fused outputs (R21): out0T (bx<256) | out1T (256<=bx<384) | omega (bx==384) ==
__global__ __launch_bounds__(256) void k_outs(const float* __restrict__ U32,
                                              const double* __restrict__ ndb,
                                              float* __restrict__ out){
    __shared__ float smem[128 * 65];
    int bx = blockIdx.x;
    int tid = threadIdx.x;
    if (bx < 256){
        // out0[(k*8192+t)*16 + ch] = y[k*16+cw][t], ch=(cw+8)&15
        float (*tile)[257] = (float(*)[257])smem;        // 16x257 <= 128x65
        int k  = bx >> 5;
        int t0 = (bx & 31) * 256;
        #pragma unroll
        for (int cw = 0; cw < 16; cw++)
            tile[cw][tid] = U32[((size_t)(k * 16 + cw)) * 16384 + t0 + tid];
        __syncthreads();
        #pragma unroll
        for (int i = 0; i < 16; i++){
            int flat = i * 256 + tid;        // flat = dt*16 + ch
            int dt = flat >> 4, ch = flat & 15;
            int cw = (ch + 8) & 15;
            out[(size_t)k * 131072 + t0 * 16 + flat] = tile[cw][dt];
        }
    } else if (bx < 384){
        // out1[1048576 + t*128 + b] = W2[b][t]
        float (*tile)[65] = (float(*)[65])smem;
        int t0 = (bx - 256) * 64;
        #pragma unroll
        for (int i = 0; i < 32; i++){
            int flat = i * 256 + tid;
            int b = flat >> 6, dt = flat & 63;
            tile[b][dt] = U32[(size_t)b * 16384 + 8192 + t0 + dt];
        }
        __syncthreads();
        #pragma unroll
        for (int i = 0; i < 32; i++){
            int flat = i * 256 + tid;
            int dt = flat >> 7, b = flat & 127;
            out[1048576 + (size_t)(t0 + dt) * 128 + b] = tile[b][dt];
        }
    } else {
        // omega history: out2 = Re(omega), 160 floats at 2097152
        int t = tid;
        if (t >= 160) return;
        int row = t >> 3, k = t & 7;
        double v;
        if (row == 0){
            v = 0.0625 * (double)k;
        } else {
            const double* r = ndb + (row - 1) * 256;
            double n_ = 0.0, d_ = 0.0;
            #pragma unroll
            for (int bk = 0; bk < ND_BANKS; bk++){
                n_ += r[bk * 16 + k];
                d_ += r[bk * 16 + 8 + k];
            }
            v = n_ / d_;
        }
        out[2097152 + t] = (float)v;
    }
}

extern "C" void kernel_launch(void* const* d_in, const int* in_sizes, int n_in,
                              void* d_out, int out_size, void* d_ws, size_t ws_size,
                              hipStream_t stream){
    const float* sig = (const float*)d_in[0];
    float* out = (float*)d_out;
    char* p = (char*)d_ws;
    // ws: U 8 MB (FPTA/FPTB alias its first 2 MB — dead before U is written) |
    //     D (NDB banks + CNT arr/rep) ~41 KB at p+8MB  => ~8.05 MB total footprint
    float2* U    = (float2*)p;
    float2* FPTA = (float2*)p;                               // alias U[0 .. 1MB)
    float2* FPTB = (float2*)(p + (size_t)1 * 1024 * 1024);   // alias U[1MB .. 2MB)
    double* D    = (double*)(p + (size_t)8 * 1024 * 1024);

    k_stageA<<<dim3(32), dim3(1024), 65536, stream>>>(sig, FPTA, FPTB, D);
    k_vmd_all<<<dim3(VMD_BLOCKS), dim3(512), 0, stream>>>(FPTA, FPTB, U, D);
    k_stageCD<<<dim3(128), dim3(1024), 65536, stream>>>(U);
    k_outs<<<dim3(385), dim3(256), 0, stream>>>((const float*)U, D, out);
}

// Round 7
// 166.213 us; speedup vs baseline: 1.4416x; 1.4416x over previous
//
#include <hip/hip_runtime.h>
#include <math.h>

#define NPAIR 131072          // 8192 freqs x 16 channels
#define STEPS 19
#define VMD_BLOCKS 256        // x 512 threads = NPAIR
#define ND_BANKS 16

// XOR swizzle: spreads strided radix-8 writes across banks; keeps contiguous free
#define SW(a) ((a) ^ (((a) >> 5) & 31))

#define LD_RLX(p)    __hip_atomic_load((p),       __ATOMIC_RELAXED, __HIP_MEMORY_SCOPE_AGENT)
#define ST_RLX(p,v)  __hip_atomic_store((p),(v),  __ATOMIC_RELAXED, __HIP_MEMORY_SCOPE_AGENT)
#define FAA_RLX(p,v) __hip_atomic_fetch_add((p),(v),__ATOMIC_RELAXED, __HIP_MEMORY_SCOPE_AGENT)

__device__ __forceinline__ float2 cadd(float2 a, float2 b){ return make_float2(a.x+b.x, a.y+b.y); }
__device__ __forceinline__ float2 csub(float2 a, float2 b){ return make_float2(a.x-b.x, a.y-b.y); }
__device__ __forceinline__ float2 cmul(float2 a, float2 b){
    return make_float2(a.x*b.x - a.y*b.y, a.x*b.y + a.y*b.x);
}
template<int SGN>
__device__ __forceinline__ float2 imul(float2 a){   // multiply by e^{SGN*i*pi/2}
    return (SGN > 0) ? make_float2(-a.y, a.x) : make_float2(a.y, -a.x);
}

// 8-point DFT: y_k = sum_r a_r e^{SGN*2pi i r k/8}
template<int SGN>
__device__ __forceinline__ void dft8(const float2* a, float2* y){
    const float C = 0.70710678118654752f;
    const float sg = (SGN > 0) ? 1.f : -1.f;
    float2 t0 = cadd(a[0], a[4]), t1 = csub(a[0], a[4]);
    float2 t2 = cadd(a[2], a[6]), t3 = imul<SGN>(csub(a[2], a[6]));
    float2 E0 = cadd(t0, t2), E2 = csub(t0, t2), E1 = cadd(t1, t3), E3 = csub(t1, t3);
    float2 s0 = cadd(a[1], a[5]), s1 = csub(a[1], a[5]);
    float2 s2 = cadd(a[3], a[7]), s3 = imul<SGN>(csub(a[3], a[7]));
    float2 O0 = cadd(s0, s2), O2 = csub(s0, s2), O1 = cadd(s1, s3), O3 = csub(s1, s3);
    float2 w1 = make_float2(C, sg * C), w3 = make_float2(-C, sg * C);
    float2 R0 = O0, R1 = cmul(O1, w1), R2 = imul<SGN>(O2), R3 = cmul(O3, w3);
    y[0] = cadd(E0, R0); y[4] = csub(E0, R0);
    y[1] = cadd(E1, R1); y[5] = csub(E1, R1);
    y[2] = cadd(E2, R2); y[6] = csub(E2, R2);
    y[3] = cadd(E3, R3); y[7] = csub(E3, R3);
}

// ===== in-LDS 8192-pt Stockham FFT: 4 radix-8 passes + 1 radix-2, 1024 threads =====
template<int SGN>
__device__ void lds_fft8192_r8(float2* lds, int tid){
    #pragma unroll
    for (int pi = 0; pi < 4; pi++){
        int ls = 3 * pi;
        int s  = 1 << ls;
        int nn = 8192 >> ls;
        int q = tid & (s - 1);
        float2 a[8], y[8];
        #pragma unroll
        for (int r = 0; r < 8; r++) a[r] = lds[SW(tid + (r << 10))];
        __syncthreads();
        dft8<SGN>(a, y);
        int p = tid >> ls;
        float ang = (float)(2 * p) / (float)nn;
        float sn, cs;
        sincospif(SGN > 0 ? ang : -ang, &sn, &cs);   // w = e^{SGN*2pi i p/nn}
        float2 w = make_float2(cs, sn);
        float2 wk = make_float2(1.f, 0.f);
        int o = q + ((tid - q) << 3);                 // q + 8*s*p
        lds[SW(o)] = y[0];
        #pragma unroll
        for (int k = 1; k < 8; k++){
            wk = cmul(wk, w);
            lds[SW(o + (k << ls))] = cmul(y[k], wk);
        }
        __syncthreads();
    }
    #pragma unroll
    for (int w4 = 0; w4 < 4; w4++){                   // final radix-2, twiddle-free
        int idx = (w4 << 10) + tid;
        float2 a = lds[SW(idx)], b = lds[SW(idx + 4096)];
        lds[SW(idx)]        = cadd(a, b);
        lds[SW(idx + 4096)] = csub(a, b);
    }
    __syncthreads();
}

// ===== stage A: mirror-extend + one FFT8192 per block (even/odd split radix half) ====
// R18: 32 blocks x 1 FFT. Split-radix combine fused into k_vmd_all's load.
// R19: FPTA/FPTB alias U's first 2 MB (dead before U written).
// R21: zero-fill of D fused here (saves a launch; kernel boundary orders it).
__global__ __launch_bounds__(1024) void k_stageA(const float* __restrict__ sig,
                                                 float2* __restrict__ FPTA,
                                                 float2* __restrict__ FPTB,
                                                 double* __restrict__ D){
    extern __shared__ float2 lds[];
    int tid  = threadIdx.x;
    int bb   = blockIdx.x;                   // bb = cw*2 + half
    // fused zerond: 32 blocks x 1024 threads cover 5400 doubles
    for (int zi = bb * 1024 + tid; zi < 5400; zi += 32768)
        D[zi] = 0.0;
    int cw   = bb >> 1, half = bb & 1;
    int cs   = (cw + 8) & 15;                // fftshift over channel axis
    const float* sp = sig + cs * 8192;
    #pragma unroll
    for (int r = 0; r < 8; r++){             // samples 2p+half of mirrored extension
        int p = r * 1024 + tid;
        int x = 2 * p + half;
        int mx = (x < 4096) ? (4095 - x) : ((x < 12288) ? (x - 4096) : (20479 - x));
        lds[SW(p)] = make_float2(sp[mx], 0.f);
    }
    __syncthreads();
    lds_fft8192_r8<-1>(lds, tid);
    float2* dst = (half == 0 ? FPTA : FPTB) + cw * 8192;
    #pragma unroll
    for (int r = 0; r < 8; r++){
        int j = r * 1024 + tid;
        dst[j] = lds[SW(j)];
    }
}

// ===== fused 19-step VMD: relaxed LLC barrier, R21 topology (PROVEN 89.6 us) ====
// R16: all cross-block data via AGENT-scope (LLC) atomics — no fences needed.
// R17: role-splitting multi-value butterfly reduce (17 dbl-shfls vs 96).
// R18/R19 LESSON: polled-line accessor count + RMW mix drive cost — never let
// 256 readers poll an RMW'd line.
// R22 LESSON: FAA arrival beats store+poll aggregation — detection of "all
// arrived" is embedded in the FAA return value (zero latency), while store+poll
// pays 1-2 poll-period quanta per step and 16x poll read traffic (160 us!).
// Barrier recipe locked: FAA for arrival, stores for release fan-out,
// single-word polls, <=16 readers per polled line.
// R23: one rcp instead of two IEEE f64 divs in the k-loop (compiler can't).
__global__ __launch_bounds__(512, 2) void k_vmd_all(const float2* __restrict__ FPTA,
                                                    const float2* __restrict__ FPTB,
                                                    float2* __restrict__ U,
                                                    double* __restrict__ D){
    double* NDB = D;
    int*    CNT = (int*)(D + 4864);

    int tid = blockIdx.x * 512 + threadIdx.x;   // [0,NPAIR), tid = cw*8192+j
    int j = tid & 8191;
    double fr = (double)j / 16384.0;
    // split-radix combine (was in stageA): F[j] = A[j] + e^{-i pi j/8192} B[j]
    float2 Av = FPTA[tid], Bv = FPTB[tid];
    float snw, cnw;
    sincospif(-(float)j / 8192.0f, &snw, &cnw);
    float2 tw = cmul(Bv, make_float2(cnw, snw));
    float2 fv = make_float2(Av.x + tw.x, Av.y + tw.y);
    double fx = fv.x, fy = fv.y;
    float urx[8], ury[8];
    double om[8];
    #pragma unroll
    for (int k = 0; k < 8; k++){ urx[k] = 0.f; ury[k] = 0.f; om[k] = 0.0625 * (double)k; }
    __shared__ double lred[8][16];
    __shared__ double ndls[256];
    __shared__ double om_s[8];
    int lane = threadIdx.x & 63, wv = threadIdx.x >> 6;
    int mybank = (blockIdx.x & (ND_BANKS - 1)) * 16;
    int grp = blockIdx.x >> 4;                  // 16 groups of 16 blocks

    for (int step = 0; step < STEPS; step++){
        if (step > 0){
            #pragma unroll
            for (int k = 0; k < 8; k++) om[k] = om_s[k];
        }
        double sx = 0.0, sy = 0.0;
        #pragma unroll
        for (int k = 1; k < 8; k++){ sx += (double)urx[k]; sy += (double)ury[k]; }
        double lx = 0.0, ly = 0.0, nloc[8], dloc[8];
        #pragma unroll
        for (int k = 0; k < 8; k++){
            if (k > 0){ sx += lx - (double)urx[k]; sy += ly - (double)ury[k]; }
            double d = fr - om[k];
            double den = 1.0 + 2000.0 * d * d;
            double rden = 1.0 / den;                  // R23: 1 div + 2 mul (was 2 divs)
            double nx = (fx - sx) * rden, ny = (fy - sy) * rden;
            urx[k] = (float)nx; ury[k] = (float)ny;   // replicate complex64 carry
            lx = nx; ly = ny;
            double pw = nx * nx + ny * ny;
            nloc[k] = fr * pw; dloc[k] = pw;
        }
        // ---- multi-value butterfly reduce: 16 doubles across 64 lanes, 17 dbl-shfls ----
        // Level A (xor 32): bit5=0 lanes keep n-values, bit5=1 keep d-values.
        double s8[8];
        {
            bool hi = (lane & 32) != 0;
            #pragma unroll
            for (int k = 0; k < 8; k++){
                double t = hi ? nloc[k] : dloc[k];          // what we give away
                double r = __shfl_xor(t, 32);
                s8[k] = (hi ? dloc[k] : nloc[k]) + r;       // what we keep
            }
        }
        // Level B (xor 16): bit4=0 keeps idx 0..3, bit4=1 keeps idx 4..7.
        double s4v[4];
        {
            bool hi = (lane & 16) != 0;
            #pragma unroll
            for (int k = 0; k < 4; k++){
                double t = hi ? s8[k] : s8[k + 4];
                double r = __shfl_xor(t, 16);
                s4v[k] = (hi ? s8[k + 4] : s8[k]) + r;
            }
        }
        // Level C (xor 8)
        double s2v[2];
        {
            bool hi = (lane & 8) != 0;
            #pragma unroll
            for (int k = 0; k < 2; k++){
                double t = hi ? s4v[k] : s4v[k + 2];
                double r = __shfl_xor(t, 8);
                s2v[k] = (hi ? s4v[k + 2] : s4v[k]) + r;
            }
        }
        // Level D (xor 4)
        double sv;
        {
            bool hi = (lane & 4) != 0;
            double t = hi ? s2v[0] : s2v[1];
            double r = __shfl_xor(t, 4);
            sv = (hi ? s2v[1] : s2v[0]) + r;
        }
        // Final two full butterflies over the remaining 4-lane replication group
        sv += __shfl_xor(sv, 2);
        sv += __shfl_xor(sv, 1);
        // lane l holds wave-total for idx = l>>2 (idx<8: n_idx, idx>=8: d_{idx-8})
        if ((lane & 3) == 0) lred[wv][lane >> 2] = sv;
        __syncthreads();
        if (threadIdx.x < 16){
            double sum = 0.0;
            #pragma unroll
            for (int w = 0; w < 8; w++) sum += lred[w][threadIdx.x];
            atomicAdd(&NDB[step * 256 + mybank + threadIdx.x], sum);  // LLC f64 atomic
        }
        __syncthreads();      // all waves vmcnt-drained -> NDB adds COMPLETE at LLC
        if (step < STEPS - 1){
            if (threadIdx.x == 0){
                int target = 16 * (step + 1);   // monotonic counters: no reset race
                int old = FAA_RLX(&CNT[grp * 32], 1);
                bool released = false;
                if (old == target - 1){         // group-last: bump root counter
                    int rold = FAA_RLX(&CNT[512], 1);
                    if (rold == target - 1){    // root-last: broadcast ALL group flags
                        #pragma unroll
                        for (int g = 0; g < 16; g++)
                            ST_RLX(&CNT[576 + g * 32], step + 1);
                        released = true;        // root-last proceeds immediately
                    }
                }
                if (!released)
                    while (LD_RLX(&CNT[576 + grp * 32]) <= step)
                        __builtin_amdgcn_s_sleep(1);
            }
            __syncthreads();
            // parallel readback: 256 threads fetch one double each (LLC), sum in LDS
            if (threadIdx.x < 256)
                ndls[threadIdx.x] = LD_RLX(&NDB[step * 256 + threadIdx.x]);
            __syncthreads();
            if (threadIdx.x < 8){
                double n_ = 0.0, d_ = 0.0;
                #pragma unroll
                for (int bk = 0; bk < ND_BANKS; bk++){
                    n_ += ndls[bk * 16 + threadIdx.x];
                    d_ += ndls[bk * 16 + 8 + threadIdx.x];
                }
                om_s[threadIdx.x] = n_ / d_;
            }
            __syncthreads();
        }
    }
    #pragma unroll
    for (int k = 0; k < 8; k++) U[k * NPAIR + tid] = make_float2(urx[k], ury[k]);
}

// ===== stage C+D (R21): real-iFFT pack — 2 FFT8192 instead of 3 =====
// y = Re(iFFT16384(H)) = iFFT16384(hermitian_part(H)). Standard N/2 pack:
//   G[k] = (H[k]+H[k+M]) + i*W^k*(H[k]-H[k+M]),  W = e^{+i pi k/8192}, M=8192
//   z = iFFT8192(G)/N  ->  y[2n]=Re z[n], y[2n+1]=Im z[n]
// H (hermitized) from pos[]: H[k]=pos[k] (1<=k<=8191), H[0]=Re(pos[0]),
// H[M]=Re(pos[8191]), H[k+M]=conj(pos[M-k]) (1<=k<=M-1).
// Slice y_full[4096..12287] = z[2048..6143] interleaved.
// After: U32[b*16384 + t] = y[t];  U32[b*16384 + 8192 + t] = Re(Yf[(t+4096) mod 8192])
__global__ __launch_bounds__(1024) void k_stageCD(float2* __restrict__ U){
    extern __shared__ float2 lds[];
    int tid = threadIdx.x;
    int b = blockIdx.x;                      // b = k*16 + cw
    const float2* pos = U + b * 8192;
    float* slice = (float*)(U) + (size_t)b * 16384;
    const float inv = 1.0f / 16384.0f;
    // build G[p]
    #pragma unroll
    for (int r = 0; r < 8; r++){
        int p = r * 1024 + tid;
        float2 Hk, HkM;
        if (p == 0){
            Hk  = make_float2(pos[0].x, 0.f);
            HkM = make_float2(pos[8191].x, 0.f);
        } else {
            Hk = pos[p];
            float2 q2 = pos[8192 - p];
            HkM = make_float2(q2.x, -q2.y);
        }
        float2 S  = cadd(Hk, HkM);
        float2 Dv = csub(Hk, HkM);
        float sn, cn;
        sincospif((float)p / 8192.0f, &sn, &cn);     // W^p = e^{+i pi p/8192}
        float2 c = cmul(make_float2(cn, sn), Dv);
        lds[SW(p)] = make_float2(S.x - c.y, S.y + c.x);   // S + i*c
    }
    __syncthreads();
    lds_fft8192_r8<1>(lds, tid);
    // z[n] -> slice (only n in [2048,6144) land in the F/4..3F/4 slice)
    float2 zreg[4];
    #pragma unroll
    for (int q = 2; q < 6; q++){
        int n = q * 1024 + tid;
        float2 z = lds[SW(n)];
        zreg[q - 2] = make_float2(z.x * inv, z.y * inv);
        *(float2*)&slice[2 * n - 4096] = zreg[q - 2];     // coalesced 8B store
    }
    __syncthreads();
    // refill lds with the slice as complex (val, 0) for the forward FFT
    #pragma unroll
    for (int q = 0; q < 4; q++){
        int n = (q + 2) * 1024 + tid;
        int t = 2 * n - 4096;
        lds[SW(t)]     = make_float2(zreg[q].x, 0.f);
        lds[SW(t + 1)] = make_float2(zreg[q].y, 0.f);
    }
    __syncthreads();
    lds_fft8192_r8<-1>(lds, tid);            // forward FFT8192 of y-slice
    #pragma unroll
    for (int q = 0; q < 8; q++){
        int t = q * 1024 + tid;
        float2 Y = lds[SW(((q + 4) & 7) * 1024 + tid)];
        slice[8192 + t] = Y.x;               // Re(Yf[(t+4096) mod 8192]), coalesced
    }
}

// ===== fused outputs (R21): out0T (bx<256) | out1T (256<=bx<384) | omega (bx==384) ==
__global__ __launch_bounds__(256) void k_outs(const float* __restrict__ U32,
                                              const double* __restrict__ ndb,
                                              float* __restrict__ out){
    __shared__ float smem[128 * 65];
    int bx = blockIdx.x;
    int tid = threadIdx.x;
    if (bx < 256){
        // out0[(k*8192+t)*16 + ch] = y[k*16+cw][t], ch=(cw+8)&15
        float (*tile)[257] = (float(*)[257])smem;        // 16x257 <= 128x65
        int k  = bx >> 5;
        int t0 = (bx & 31) * 256;
        #pragma unroll
        for (int cw = 0; cw < 16; cw++)
            tile[cw][tid] = U32[((size_t)(k * 16 + cw)) * 16384 + t0 + tid];
        __syncthreads();
        #pragma unroll
        for (int i = 0; i < 16; i++){
            int flat = i * 256 + tid;        // flat = dt*16 + ch
            int dt = flat >> 4, ch = flat & 15;
            int cw = (ch + 8) & 15;
            out[(size_t)k * 131072 + t0 * 16 + flat] = tile[cw][dt];
        }
    } else if (bx < 384){
        // out1[1048576 + t*128 + b] = W2[b][t]
        float (*tile)[65] = (float(*)[65])smem;
        int t0 = (bx - 256) * 64;
        #pragma unroll
        for (int i = 0; i < 32; i++){
            int flat = i * 256 + tid;
            int b = flat >> 6, dt = flat & 63;
            tile[b][dt] = U32[(size_t)b * 16384 + 8192 + t0 + dt];
        }
        __syncthreads();
        #pragma unroll
        for (int i = 0; i < 32; i++){
            int flat = i * 256 + tid;
            int dt = flat >> 7, b = flat & 127;
            out[1048576 + (size_t)(t0 + dt) * 128 + b] = tile[b][dt];
        }
    } else {
        // omega history: out2 = Re(omega), 160 floats at 2097152
        int t = tid;
        if (t >= 160) return;
        int row = t >> 3, k = t & 7;
        double v;
        if (row == 0){
            v = 0.0625 * (double)k;
        } else {
            const double* r = ndb + (row - 1) * 256;
            double n_ = 0.0, d_ = 0.0;
            #pragma unroll
            for (int bk = 0; bk < ND_BANKS; bk++){
                n_ += r[bk * 16 + k];
                d_ += r[bk * 16 + 8 + k];
            }
            v = n_ / d_;
        }
        out[2097152 + t] = (float)v;
    }
}

extern "C" void kernel_launch(void* const* d_in, const int* in_sizes, int n_in,
                              void* d_out, int out_size, void* d_ws, size_t ws_size,
                              hipStream_t stream){
    const float* sig = (const float*)d_in[0];
    float* out = (float*)d_out;
    char* p = (char*)d_ws;
    // ws: U 8 MB (FPTA/FPTB alias its first 2 MB — dead before U is written) |
    //     D (NDB banks + CNT/flags) ~43 KB at p+8MB  => ~8.05 MB total footprint
    float2* U    = (float2*)p;
    float2* FPTA = (float2*)p;                               // alias U[0 .. 1MB)
    float2* FPTB = (float2*)(p + (size_t)1 * 1024 * 1024);   // alias U[1MB .. 2MB)
    double* D    = (double*)(p + (size_t)8 * 1024 * 1024);

    k_stageA<<<dim3(32), dim3(1024), 65536, stream>>>(sig, FPTA, FPTB, D);
    k_vmd_all<<<dim3(VMD_BLOCKS), dim3(512), 0, stream>>>(FPTA, FPTB, U, D);
    k_stageCD<<<dim3(128), dim3(1024), 65536, stream>>>(U);
    k_outs<<<dim3(385), dim3(256), 0, stream>>>((const float*)U, D, out);
}